// Round 1
// baseline (450.110 us; speedup 1.0000x reference)
//
#include <hip/hip_runtime.h>
#include <hip/hip_bf16.h>

// ---------------------------------------------------------------------------
// Fused FlaxLLaMAAttention for MI355X (gfx950).
// B=1 S=2048 D=2048 H=32 KVH=8 HD=64, fp32 in/out, bf16 MFMA internals.
//
// Pipeline (all on `stream`, scratch in d_ws, ~53 MB used):
//   k_cast      : hidden fp32 -> bf16                      [2048][2048]
//   k_tcast x4  : wq/wk/wv -> wqkvT bf16 [3072][2048]; wo -> woT [2048][2048]
//   k_table     : cos/sin table [2048][32] float2 from position_ids
//   k_gemm      : xqkv = hidden @ wqkv   (bf16 out, [2048][3072])
//   k_rope      : rope(q)*0.125 -> xq, rope(k) -> xk
//   k_vt        : v part transposed -> xvT [512][2048]
//   k_attn      : causal GQA flash attention -> attnout bf16 [2048][2048]
//   k_gemm      : out = attnout @ wo     (fp32 out -> d_out)
// ---------------------------------------------------------------------------

using short8  = __attribute__((ext_vector_type(8))) short;
using f32x4   = __attribute__((ext_vector_type(4))) float;
using f32x2   = __attribute__((ext_vector_type(2))) float;
using ushort4v= __attribute__((ext_vector_type(4))) unsigned short;

#define SEQ 2048
#define DIM 2048
#define NH  32
#define NKVH 8
#define HD  64
#define KVD 512      // NKVH*HD
#define NQKV 3072    // DIM + 2*KVD

__device__ __forceinline__ float bf2f(unsigned short u) {
  union { float f; unsigned v; } x; x.v = ((unsigned)u) << 16; return x.f;
}
__device__ __forceinline__ unsigned short f2bf(float f) {
  union { float f; unsigned v; } x; x.f = f;
  unsigned r = x.v + 0x7fffu + ((x.v >> 16) & 1u);   // round-nearest-even
  return (unsigned short)(r >> 16);
}

// ---------------- elementwise cast fp32 -> bf16 (vectorized) ----------------
__global__ __launch_bounds__(256) void k_cast(const float* __restrict__ src,
                                              unsigned short* __restrict__ dst, int n) {
  int idx = (blockIdx.x * 256 + threadIdx.x) * 4;
  if (idx < n) {
    f32x4 v = *(const f32x4*)(src + idx);
    ushort4v o;
    o[0] = f2bf(v[0]); o[1] = f2bf(v[1]); o[2] = f2bf(v[2]); o[3] = f2bf(v[3]);
    *(ushort4v*)(dst + idx) = o;
  }
}

// ---------------- transpose + cast: src fp32 [R=2048][C] -> dst bf16 [C][2048]
__global__ __launch_bounds__(256) void k_tcast(const float* __restrict__ src, int C,
                                               unsigned short* __restrict__ dst) {
  __shared__ float tile[32][33];
  int c0 = blockIdx.x * 32, r0 = blockIdx.y * 32;
  int tx = threadIdx.x, ty = threadIdx.y;   // 32x8
  #pragma unroll
  for (int j = 0; j < 32; j += 8)
    tile[ty + j][tx] = src[(r0 + ty + j) * C + c0 + tx];
  __syncthreads();
  #pragma unroll
  for (int j = 0; j < 32; j += 8)
    dst[(c0 + ty + j) * 2048 + r0 + tx] = f2bf(tile[tx][ty + j]);
}

// ---------------- rope cos/sin table: tab[s][p] = (cos,sin)(pos[s]*freq_p) ---
__global__ __launch_bounds__(256) void k_table(const int* __restrict__ pos,
                                               f32x2* __restrict__ tab) {
  int i = blockIdx.x * 256 + threadIdx.x;   // 2048*32
  int s = i >> 5, p = i & 31;
  float freq = powf(10000.0f, -(float)(2 * p) / 64.0f);
  float ang = (float)pos[s] * freq;
  float sv, cv; sincosf(ang, &sv, &cv);
  f32x2 r; r[0] = cv; r[1] = sv;
  tab[i] = r;
}

// ---------------- bf16 GEMM: C[M=2048][N] = A[2048][2048] * Bt[N][2048]^T ----
// 128x128 tile, BK=64, 4 waves (2x2), 16x16x32 bf16 MFMA, reg-staged LDS.
template <int N, bool OUTF32>
__global__ __launch_bounds__(256) void k_gemm(const unsigned short* __restrict__ A,
                                              const unsigned short* __restrict__ Bt,
                                              void* __restrict__ Cout) {
  const int K = 2048;
  __shared__ unsigned short lA[128 * 64];
  __shared__ unsigned short lB[128 * 64];
  int m0 = blockIdx.y * 128, n0 = blockIdx.x * 128;
  int t = threadIdx.x, lane = t & 63, wid = t >> 6;
  int wr = wid >> 1, wc = wid & 1;          // wave 64x64 sub-tile
  int lr = lane & 15, lg = lane >> 4;

  f32x4 acc[4][4] = {};

  for (int k0 = 0; k0 < K; k0 += 64) {
    short8 va[4], vb[4];
    #pragma unroll
    for (int j = 0; j < 4; ++j) {
      int c = t + 256 * j, row = c >> 3, cc = c & 7;
      va[j] = *(const short8*)(A  + (m0 + row) * K + k0 + cc * 8);
      vb[j] = *(const short8*)(Bt + (n0 + row) * K + k0 + cc * 8);
    }
    __syncthreads();                         // prior compute done before overwrite
    #pragma unroll
    for (int j = 0; j < 4; ++j) {
      int c = t + 256 * j;
      *(short8*)(lA + c * 8) = va[j];
      *(short8*)(lB + c * 8) = vb[j];
    }
    __syncthreads();
    #pragma unroll
    for (int kk = 0; kk < 64; kk += 32) {
      short8 af[4], bfr[4];
      #pragma unroll
      for (int i = 0; i < 4; ++i) {
        af[i]  = *(const short8*)(lA + (wr * 64 + i * 16 + lr) * 64 + kk + lg * 8);
        bfr[i] = *(const short8*)(lB + (wc * 64 + i * 16 + lr) * 64 + kk + lg * 8);
      }
      #pragma unroll
      for (int i = 0; i < 4; ++i)
        #pragma unroll
        for (int j = 0; j < 4; ++j)
          acc[i][j] = __builtin_amdgcn_mfma_f32_16x16x32_bf16(af[i], bfr[j], acc[i][j], 0, 0, 0);
    }
  }
  // epilogue: C layout col=lane&15, row=(lane>>4)*4+reg  [verified m89/m91]
  #pragma unroll
  for (int i = 0; i < 4; ++i)
    #pragma unroll
    for (int j = 0; j < 4; ++j)
      #pragma unroll
      for (int r = 0; r < 4; ++r) {
        int row = m0 + wr * 64 + i * 16 + lg * 4 + r;
        int col = n0 + wc * 64 + j * 16 + lr;
        float v = acc[i][j][r];
        if constexpr (OUTF32) ((float*)Cout)[row * N + col] = v;
        else ((unsigned short*)Cout)[row * N + col] = f2bf(v);
      }
}

// ---------------- rope split: xqkv -> xq (roped, *0.125), xk (roped) ---------
__global__ __launch_bounds__(256) void k_rope(const unsigned short* __restrict__ xqkv,
                                              const f32x2* __restrict__ tab,
                                              unsigned short* __restrict__ xq,
                                              unsigned short* __restrict__ xk) {
  int s = blockIdx.y;
  int j = blockIdx.x * 256 + threadIdx.x;   // 0..1279 pair index
  bool isq = j < 1024;
  int col = isq ? (2 * j) : (DIM + 2 * (j - 1024));
  int p = (col >> 1) & 31;
  f32x2 cs = tab[s * 32 + p];
  unsigned both = *(const unsigned*)(xqkv + s * NQKV + col);
  float a = bf2f((unsigned short)(both & 0xffff));
  float b = bf2f((unsigned short)(both >> 16));
  float ra = a * cs[0] - b * cs[1];
  float rb = a * cs[1] + b * cs[0];
  if (isq) { ra *= 0.125f; rb *= 0.125f; }   // fold 1/sqrt(HD), exact pow2
  unsigned pk = (unsigned)f2bf(ra) | ((unsigned)f2bf(rb) << 16);
  if (isq) *(unsigned*)(xq + s * DIM + col) = pk;
  else     *(unsigned*)(xk + s * KVD + (col - DIM)) = pk;
}

// ---------------- v transpose: xqkv cols [2560,3072) -> xvT [512][2048] ------
__global__ __launch_bounds__(256) void k_vt(const unsigned short* __restrict__ xqkv,
                                            unsigned short* __restrict__ xvT) {
  __shared__ unsigned short tile[32][33];
  int c0 = blockIdx.x * 32, s0 = blockIdx.y * 32;
  int tx = threadIdx.x, ty = threadIdx.y;   // 32x8
  #pragma unroll
  for (int j = 0; j < 32; j += 8)
    tile[ty + j][tx] = xqkv[(s0 + ty + j) * NQKV + 2560 + c0 + tx];
  __syncthreads();
  #pragma unroll
  for (int j = 0; j < 32; j += 8)
    xvT[(c0 + ty + j) * SEQ + s0 + tx] = tile[tx][ty + j];
}

// ---------------- causal GQA flash attention --------------------------------
// block = 4 waves = 4 q-heads of one kv-head, same 16-row q block.
// Per wave: Q [16][64] in regs, KV-step 32, online softmax fp32,
// P -> 1KB LDS -> A-frag, V from xvT (contiguous loads).
__global__ __launch_bounds__(256) void k_attn(const unsigned short* __restrict__ xq,
                                              const unsigned short* __restrict__ xk,
                                              const unsigned short* __restrict__ xvT,
                                              unsigned short* __restrict__ attnout) {
  __shared__ unsigned short plds[4][16 * 32];
  int qb = blockIdx.x & 127, kvh = blockIdx.x >> 7;
  int wid = threadIdx.x >> 6, lane = threadIdx.x & 63;
  int h = kvh * 4 + wid;
  int q0 = qb * 16;
  int lr = lane & 15, lg = lane >> 4;
  unsigned short* pw = plds[wid];

  short8 qa[2];
  #pragma unroll
  for (int ks = 0; ks < 2; ++ks)
    qa[ks] = *(const short8*)(xq + (q0 + lr) * DIM + h * HD + ks * 32 + lg * 8);

  f32x4 o[4] = {};
  float m[4], l[4];
  #pragma unroll
  for (int r = 0; r < 4; ++r) { m[r] = -3.0e38f; l[r] = 0.0f; }

  for (int kv0 = 0; kv0 <= q0; kv0 += 32) {
    // --- S = Q K^T  (S layout: col kv = lr, row q = lg*4+r) ---
    f32x4 sc[2] = {};
    #pragma unroll
    for (int nt = 0; nt < 2; ++nt) {
      int krow = kv0 + nt * 16 + lr;
      krow = min(krow, SEQ - 1);            // clamp (masked anyway) — no OOB
      #pragma unroll
      for (int ks = 0; ks < 2; ++ks) {
        short8 kb = *(const short8*)(xk + krow * KVD + kvh * HD + ks * 32 + lg * 8);
        sc[nt] = __builtin_amdgcn_mfma_f32_16x16x32_bf16(qa[ks], kb, sc[nt], 0, 0, 0);
      }
    }
    // --- causal mask (only last iteration triggers) ---
    if (kv0 + 31 > q0) {
      #pragma unroll
      for (int nt = 0; nt < 2; ++nt)
        #pragma unroll
        for (int r = 0; r < 4; ++r)
          if (kv0 + nt * 16 + lr > q0 + lg * 4 + r) sc[nt][r] = -3.0e38f;
    }
    // --- online softmax (row stats across the 16-lane group) ---
    float ps[2][4];
    #pragma unroll
    for (int r = 0; r < 4; ++r) {
      float mx = fmaxf(sc[0][r], sc[1][r]);
      mx = fmaxf(mx, __shfl_xor(mx, 1));
      mx = fmaxf(mx, __shfl_xor(mx, 2));
      mx = fmaxf(mx, __shfl_xor(mx, 4));
      mx = fmaxf(mx, __shfl_xor(mx, 8));
      float mn = fmaxf(m[r], mx);
      float scale = __expf(m[r] - mn);
      float p0 = __expf(sc[0][r] - mn);
      float p1 = __expf(sc[1][r] - mn);
      ps[0][r] = p0; ps[1][r] = p1;
      float rs = p0 + p1;
      rs += __shfl_xor(rs, 1);
      rs += __shfl_xor(rs, 2);
      rs += __shfl_xor(rs, 4);
      rs += __shfl_xor(rs, 8);
      l[r] = l[r] * scale + rs;
      m[r] = mn;
      #pragma unroll
      for (int nt2 = 0; nt2 < 4; ++nt2) o[nt2][r] *= scale;
    }
    // --- P (C layout) -> LDS -> A layout ---
    #pragma unroll
    for (int nt = 0; nt < 2; ++nt)
      #pragma unroll
      for (int r = 0; r < 4; ++r)
        pw[(lg * 4 + r) * 32 + nt * 16 + lr] = f2bf(ps[nt][r]);
    asm volatile("s_waitcnt lgkmcnt(0)" ::: "memory");
    short8 pa = *(const short8*)(pw + lr * 32 + lg * 8);
    // --- O += P V ---
    int vc = min(kv0 + lg * 8, SEQ - 8);    // clamp (P=0 for masked kv)
    #pragma unroll
    for (int nt2 = 0; nt2 < 4; ++nt2) {
      short8 vb = *(const short8*)(xvT + (kvh * HD + nt2 * 16 + lr) * SEQ + vc);
      o[nt2] = __builtin_amdgcn_mfma_f32_16x16x32_bf16(pa, vb, o[nt2], 0, 0, 0);
    }
  }
  // --- epilogue: O / l ---
  #pragma unroll
  for (int nt2 = 0; nt2 < 4; ++nt2)
    #pragma unroll
    for (int r = 0; r < 4; ++r) {
      float v = o[nt2][r] / l[r];
      attnout[(q0 + lg * 4 + r) * DIM + h * HD + nt2 * 16 + lr] = f2bf(v);
    }
}

// ---------------------------------------------------------------------------
extern "C" void kernel_launch(void* const* d_in, const int* in_sizes, int n_in,
                              void* d_out, int out_size, void* d_ws, size_t ws_size,
                              hipStream_t stream) {
  const float* hs = (const float*)d_in[0];
  const float* wq = (const float*)d_in[1];
  const float* wk = (const float*)d_in[2];
  const float* wv = (const float*)d_in[3];
  const float* wo = (const float*)d_in[4];
  const int* pos  = (const int*)d_in[5];
  float* out = (float*)d_out;

  char* ws = (char*)d_ws;
  // layout (bytes): total ~52.5 MiB
  unsigned short* wqkvT = (unsigned short*)(ws);                    // 3072*2048*2 = 12582912
  unsigned short* woT   = (unsigned short*)(ws + 12582912);         // 2048*2048*2 =  8388608
  unsigned short* hbf   = (unsigned short*)(ws + 20971520);         //               8388608
  unsigned short* xqkv  = (unsigned short*)(ws + 29360128);         // 2048*3072*2 = 12582912
  unsigned short* xq    = (unsigned short*)(ws + 41943040);         //               8388608
  unsigned short* xk    = (unsigned short*)(ws + 50331648);         //               2097152
  unsigned short* xvT   = (unsigned short*)(ws + 52428800);         //               2097152
  f32x2*          tab   = (f32x2*)(ws + 54525952);                  //                524288
  unsigned short* attnout = hbf;  // hbf dead after first GEMM — reuse

  k_cast<<<4096, 256, 0, stream>>>(hs, hbf, SEQ * DIM);
  k_tcast<<<dim3(64, 64), dim3(32, 8), 0, stream>>>(wq, 2048, wqkvT);
  k_tcast<<<dim3(16, 64), dim3(32, 8), 0, stream>>>(wk, 512, wqkvT + 2048 * 2048);
  k_tcast<<<dim3(16, 64), dim3(32, 8), 0, stream>>>(wv, 512, wqkvT + 2560 * 2048);
  k_tcast<<<dim3(64, 64), dim3(32, 8), 0, stream>>>(wo, 2048, woT);
  k_table<<<256, 256, 0, stream>>>(pos, tab);

  k_gemm<NQKV, false><<<dim3(NQKV / 128, SEQ / 128), 256, 0, stream>>>(hbf, wqkvT, xqkv);

  k_rope<<<dim3(5, SEQ), 256, 0, stream>>>(xqkv, tab, xq, xk);
  k_vt<<<dim3(16, 64), dim3(32, 8), 0, stream>>>(xqkv, xvT);

  k_attn<<<1024, 256, 0, stream>>>(xq, xk, xvT, attnout);

  k_gemm<DIM, true><<<dim3(DIM / 128, SEQ / 128), 256, 0, stream>>>(attnout, woT, out);
}

// Round 3
// 295.997 us; speedup vs baseline: 1.5207x; 1.5207x over previous
//
#include <hip/hip_runtime.h>
#include <hip/hip_bf16.h>

// ---------------------------------------------------------------------------
// Fused FlaxLLaMAAttention for MI355X (gfx950).
// B=1 S=2048 D=2048 H=32 KVH=8 HD=64, fp32 in/out, bf16 MFMA internals.
//
// Round 2 (resubmit; round-2 bench was an infra timeout): attention in
// swapped-QK 32x32 in-register-softmax structure (no LDS, no barriers,
// uniform 65-step waves); GEMM staging via global_load_lds width=16 (m97).
// ---------------------------------------------------------------------------

using short8  = __attribute__((ext_vector_type(8))) short;
using f32x4   = __attribute__((ext_vector_type(4))) float;
using f32x16  = __attribute__((ext_vector_type(16))) float;
using f32x2   = __attribute__((ext_vector_type(2))) float;
using ushort4v= __attribute__((ext_vector_type(4))) unsigned short;

#define SEQ 2048
#define DIM 2048
#define NH  32
#define NKVH 8
#define HD  64
#define KVD 512      // NKVH*HD
#define NQKV 3072    // DIM + 2*KVD

#define GLOAD_LDS16(g, l) \
  __builtin_amdgcn_global_load_lds((const __attribute__((address_space(1))) void*)(g), \
                                   (__attribute__((address_space(3))) void*)(l), 16, 0, 0)

__device__ __forceinline__ float bf2f(unsigned short u) {
  union { float f; unsigned v; } x; x.v = ((unsigned)u) << 16; return x.f;
}
__device__ __forceinline__ unsigned short f2bf(float f) {
  union { float f; unsigned v; } x; x.f = f;
  unsigned r = x.v + 0x7fffu + ((x.v >> 16) & 1u);   // round-nearest-even
  return (unsigned short)(r >> 16);
}

// ---------------- elementwise cast fp32 -> bf16 (vectorized) ----------------
__global__ __launch_bounds__(256) void k_cast(const float* __restrict__ src,
                                              unsigned short* __restrict__ dst, int n) {
  int idx = (blockIdx.x * 256 + threadIdx.x) * 4;
  if (idx < n) {
    f32x4 v = *(const f32x4*)(src + idx);
    ushort4v o;
    o[0] = f2bf(v[0]); o[1] = f2bf(v[1]); o[2] = f2bf(v[2]); o[3] = f2bf(v[3]);
    *(ushort4v*)(dst + idx) = o;
  }
}

// ---------------- transpose + cast: src fp32 [R=2048][C] -> dst bf16 [C][2048]
__global__ __launch_bounds__(256) void k_tcast(const float* __restrict__ src, int C,
                                               unsigned short* __restrict__ dst) {
  __shared__ float tile[32][33];
  int c0 = blockIdx.x * 32, r0 = blockIdx.y * 32;
  int tx = threadIdx.x, ty = threadIdx.y;   // 32x8
  #pragma unroll
  for (int j = 0; j < 32; j += 8)
    tile[ty + j][tx] = src[(r0 + ty + j) * C + c0 + tx];
  __syncthreads();
  #pragma unroll
  for (int j = 0; j < 32; j += 8)
    dst[(c0 + ty + j) * 2048 + r0 + tx] = f2bf(tile[tx][ty + j]);
}

// ---------------- rope cos/sin table: tab[s][p] = (cos,sin)(pos[s]*freq_p) ---
__global__ __launch_bounds__(256) void k_table(const int* __restrict__ pos,
                                               f32x2* __restrict__ tab) {
  int i = blockIdx.x * 256 + threadIdx.x;   // 2048*32
  int s = i >> 5, p = i & 31;
  float freq = powf(10000.0f, -(float)(2 * p) / 64.0f);
  float ang = (float)pos[s] * freq;
  float sv, cv; sincosf(ang, &sv, &cv);
  f32x2 r; r[0] = cv; r[1] = sv;
  tab[i] = r;
}

// ---------------- bf16 GEMM: C[M=2048][N] = A[2048][2048] * Bt[N][2048]^T ----
// 128x128 tile, BK=64, 4 waves (2x2), 16x16x32 bf16 MFMA,
// global_load_lds width=16 staging (m97 structure).
template <int N, bool OUTF32>
__global__ __launch_bounds__(256) void k_gemm(const unsigned short* __restrict__ A,
                                              const unsigned short* __restrict__ Bt,
                                              void* __restrict__ Cout) {
  const int K = 2048;
  __shared__ unsigned short lA[128 * 64];
  __shared__ unsigned short lB[128 * 64];
  int m0 = blockIdx.y * 128, n0 = blockIdx.x * 128;
  int t = threadIdx.x, lane = t & 63, wid = t >> 6;
  int wr = wid >> 1, wc = wid & 1;          // wave 64x64 sub-tile
  int lr = lane & 15, lg = lane >> 4;

  f32x4 acc[4][4] = {};

  for (int k0 = 0; k0 < K; k0 += 64) {
    // stage A+B tiles direct to LDS (linear layout matches lane order)
    #pragma unroll
    for (int j = 0; j < 4; ++j) {
      int idx = t + 256 * j, row = idx >> 3, c8 = idx & 7;
      GLOAD_LDS16(A  + (m0 + row) * K + k0 + c8 * 8, lA + idx * 8);
      GLOAD_LDS16(Bt + (n0 + row) * K + k0 + c8 * 8, lB + idx * 8);
    }
    __syncthreads();                         // vmcnt(0) drain + barrier
    #pragma unroll
    for (int kk = 0; kk < 64; kk += 32) {
      short8 af[4], bfr[4];
      #pragma unroll
      for (int i = 0; i < 4; ++i) {
        af[i]  = *(const short8*)(lA + (wr * 64 + i * 16 + lr) * 64 + kk + lg * 8);
        bfr[i] = *(const short8*)(lB + (wc * 64 + i * 16 + lr) * 64 + kk + lg * 8);
      }
      #pragma unroll
      for (int i = 0; i < 4; ++i)
        #pragma unroll
        for (int j = 0; j < 4; ++j)
          acc[i][j] = __builtin_amdgcn_mfma_f32_16x16x32_bf16(af[i], bfr[j], acc[i][j], 0, 0, 0);
    }
    __syncthreads();                         // compute done before next overwrite
  }
  // epilogue: C layout col=lane&15, row=(lane>>4)*4+reg  [verified m89/m91]
  #pragma unroll
  for (int i = 0; i < 4; ++i)
    #pragma unroll
    for (int j = 0; j < 4; ++j)
      #pragma unroll
      for (int r = 0; r < 4; ++r) {
        int row = m0 + wr * 64 + i * 16 + lg * 4 + r;
        int col = n0 + wc * 64 + j * 16 + lr;
        float v = acc[i][j][r];
        if constexpr (OUTF32) ((float*)Cout)[row * N + col] = v;
        else ((unsigned short*)Cout)[row * N + col] = f2bf(v);
      }
}

// ---------------- rope split: xqkv -> xq (roped, *0.125), xk (roped) ---------
__global__ __launch_bounds__(256) void k_rope(const unsigned short* __restrict__ xqkv,
                                              const f32x2* __restrict__ tab,
                                              unsigned short* __restrict__ xq,
                                              unsigned short* __restrict__ xk) {
  int s = blockIdx.y;
  int j = blockIdx.x * 256 + threadIdx.x;   // 0..1279 pair index
  bool isq = j < 1024;
  int col = isq ? (2 * j) : (DIM + 2 * (j - 1024));
  int p = (col >> 1) & 31;
  f32x2 cs = tab[s * 32 + p];
  unsigned both = *(const unsigned*)(xqkv + s * NQKV + col);
  float a = bf2f((unsigned short)(both & 0xffff));
  float b = bf2f((unsigned short)(both >> 16));
  float ra = a * cs[0] - b * cs[1];
  float rb = a * cs[1] + b * cs[0];
  if (isq) { ra *= 0.125f; rb *= 0.125f; }   // fold 1/sqrt(HD), exact pow2
  unsigned pk = (unsigned)f2bf(ra) | ((unsigned)f2bf(rb) << 16);
  if (isq) *(unsigned*)(xq + s * DIM + col) = pk;
  else     *(unsigned*)(xk + s * KVD + (col - DIM)) = pk;
}

// ---------------- v transpose: xqkv cols [2560,3072) -> xvT [512][2048] ------
__global__ __launch_bounds__(256) void k_vt(const unsigned short* __restrict__ xqkv,
                                            unsigned short* __restrict__ xvT) {
  __shared__ unsigned short tile[32][33];
  int c0 = blockIdx.x * 32, s0 = blockIdx.y * 32;
  int tx = threadIdx.x, ty = threadIdx.y;   // 32x8
  #pragma unroll
  for (int j = 0; j < 32; j += 8)
    tile[ty + j][tx] = xqkv[(s0 + ty + j) * NQKV + 2560 + c0 + tx];
  __syncthreads();
  #pragma unroll
  for (int j = 0; j < 32; j += 8)
    xvT[(c0 + ty + j) * SEQ + s0 + tx] = tile[tx][ty + j];
}

// ---------------- causal GQA flash attention (swapped-QK, in-register) ------
// 1024 waves, each handles head h and q-blocks {j, 63-j} -> uniform 65 steps.
// Per 32-kv step: S^T = mfma32x32x16(K,Q) so lane owns q=lane&31, 16 kv regs.
// Softmax in-register; P->A-frag via v_cvt_pk_bf16_f32 + shfl_xor(32).
__global__ __launch_bounds__(256) void k_attn(const unsigned short* __restrict__ xq,
                                              const unsigned short* __restrict__ xk,
                                              const unsigned short* __restrict__ xvT,
                                              unsigned short* __restrict__ attnout) {
  int wid = threadIdx.x >> 6, lane = threadIdx.x & 63;
  int tid = blockIdx.x * 4 + wid;           // 0..1023
  int h = tid >> 5, j = tid & 31;
  int kvh = h >> 2;
  int lq = lane & 31, hi = lane >> 5;

  #pragma unroll
  for (int ph = 0; ph < 2; ++ph) {
    int qb = ph ? (63 - j) : j;
    int q0 = qb * 32;

    // Q B-frags: 4 k-slices, lane holds q-row q0+lq, k = s*16 + hi*8 + [0..7]
    short8 qf[4];
    #pragma unroll
    for (int s = 0; s < 4; ++s)
      qf[s] = *(const short8*)(xq + (q0 + lq) * DIM + h * HD + s * 16 + hi * 8);

    f32x16 o0 = {}, o1 = {};                // O[q(reg)][d = half*32 + lq]
    float m = -3.0e38f, l = 0.0f;

    for (int kv0 = 0; kv0 <= q0; kv0 += 32) {
      // --- S^T = K Q^T : D[row=kv][col=q]; col=lq, row=(r&3)+8*(r>>2)+4*hi
      f32x16 st = {};
      #pragma unroll
      for (int s = 0; s < 4; ++s) {
        short8 kf = *(const short8*)(xk + (kv0 + lq) * KVD + kvh * HD + s * 16 + hi * 8);
        st = __builtin_amdgcn_mfma_f32_32x32x16_bf16(kf, qf[s], st, 0, 0, 0);
      }
      // --- causal mask: only the diagonal block is partial ---
      if (kv0 == q0) {
        #pragma unroll
        for (int r = 0; r < 16; ++r) {
          int kvl = (r & 3) + 8 * (r >> 2) + 4 * hi;
          if (kvl > lq) st[r] = -3.0e38f;
        }
      }
      // --- row max (lane owns q=lq; own 16 kv + partner half) ---
      float pmax = st[0];
      #pragma unroll
      for (int r = 1; r < 16; ++r) pmax = fmaxf(pmax, st[r]);
      pmax = fmaxf(pmax, __shfl_xor(pmax, 32));
      // --- defer-max rescale (THR=8) ---
      if (!__all(pmax - m <= 8.0f)) {
        float mnew = fmaxf(m, pmax);
        float scale = __expf(m - mnew);
        #pragma unroll
        for (int r = 0; r < 16; ++r) {
          int ql = (r & 3) + 8 * (r >> 2) + 4 * hi;
          float sc = __shfl(scale, ql);
          o0[r] *= sc; o1[r] *= sc;
        }
        l *= scale;
        m = mnew;
      }
      // --- P = exp(S - m), partial row-sum ---
      float p[16], sum = 0.0f;
      #pragma unroll
      for (int r = 0; r < 16; ++r) { p[r] = __expf(st[r] - m); sum += p[r]; }
      l += sum;
      // --- pack to bf16 pairs ---
      unsigned w[8];
      #pragma unroll
      for (int i = 0; i < 8; ++i)
        asm("v_cvt_pk_bf16_f32 %0, %1, %2" : "=v"(w[i]) : "v"(p[2 * i]), "v"(p[2 * i + 1]));
      // --- two PV k-slices (kv 0..15, 16..31) ---
      #pragma unroll
      for (int s2 = 0; s2 < 2; ++s2) {
        int b = s2 * 4;
        unsigned sw0 = __shfl_xor(w[b + 0], 32);
        unsigned sw1 = __shfl_xor(w[b + 1], 32);
        unsigned sw2 = __shfl_xor(w[b + 2], 32);
        unsigned sw3 = __shfl_xor(w[b + 3], 32);
        union { unsigned u[4]; short8 s8; } pa;
        pa.u[0] = hi ? sw2 : w[b + 0];
        pa.u[1] = hi ? sw3 : w[b + 1];
        pa.u[2] = hi ? w[b + 2] : sw0;
        pa.u[3] = hi ? w[b + 3] : sw1;
        short8 v0 = *(const short8*)(xvT + (kvh * HD + lq)      * SEQ + kv0 + s2 * 16 + hi * 8);
        short8 v1 = *(const short8*)(xvT + (kvh * HD + 32 + lq) * SEQ + kv0 + s2 * 16 + hi * 8);
        o0 = __builtin_amdgcn_mfma_f32_32x32x16_bf16(pa.s8, v0, o0, 0, 0, 0);
        o1 = __builtin_amdgcn_mfma_f32_32x32x16_bf16(pa.s8, v1, o1, 0, 0, 0);
      }
    }
    // --- epilogue: combine l halves, divide, store ---
    float lt = l + __shfl_xor(l, 32);
    float linv = 1.0f / lt;
    #pragma unroll
    for (int r = 0; r < 16; ++r) {
      int ql = (r & 3) + 8 * (r >> 2) + 4 * hi;
      float li = __shfl(linv, ql);
      int row = q0 + ql;
      attnout[row * DIM + h * HD + lq]      = f2bf(o0[r] * li);
      attnout[row * DIM + h * HD + 32 + lq] = f2bf(o1[r] * li);
    }
  }
}

// ---------------------------------------------------------------------------
extern "C" void kernel_launch(void* const* d_in, const int* in_sizes, int n_in,
                              void* d_out, int out_size, void* d_ws, size_t ws_size,
                              hipStream_t stream) {
  const float* hs = (const float*)d_in[0];
  const float* wq = (const float*)d_in[1];
  const float* wk = (const float*)d_in[2];
  const float* wv = (const float*)d_in[3];
  const float* wo = (const float*)d_in[4];
  const int* pos  = (const int*)d_in[5];
  float* out = (float*)d_out;

  char* ws = (char*)d_ws;
  unsigned short* wqkvT = (unsigned short*)(ws);                    // 12582912 B
  unsigned short* woT   = (unsigned short*)(ws + 12582912);         //  8388608 B
  unsigned short* hbf   = (unsigned short*)(ws + 20971520);         //  8388608 B
  unsigned short* xqkv  = (unsigned short*)(ws + 29360128);         // 12582912 B
  unsigned short* xq    = (unsigned short*)(ws + 41943040);         //  8388608 B
  unsigned short* xk    = (unsigned short*)(ws + 50331648);         //  2097152 B
  unsigned short* xvT   = (unsigned short*)(ws + 52428800);         //  2097152 B
  f32x2*          tab   = (f32x2*)(ws + 54525952);                  //   524288 B
  unsigned short* attnout = hbf;  // hbf dead after first GEMM — reuse

  k_cast<<<4096, 256, 0, stream>>>(hs, hbf, SEQ * DIM);
  k_tcast<<<dim3(64, 64), dim3(32, 8), 0, stream>>>(wq, 2048, wqkvT);
  k_tcast<<<dim3(16, 64), dim3(32, 8), 0, stream>>>(wk, 512, wqkvT + 2048 * 2048);
  k_tcast<<<dim3(16, 64), dim3(32, 8), 0, stream>>>(wv, 512, wqkvT + 2560 * 2048);
  k_tcast<<<dim3(64, 64), dim3(32, 8), 0, stream>>>(wo, 2048, woT);
  k_table<<<256, 256, 0, stream>>>(pos, tab);

  k_gemm<NQKV, false><<<dim3(NQKV / 128, SEQ / 128), 256, 0, stream>>>(hbf, wqkvT, xqkv);

  k_rope<<<dim3(5, SEQ), 256, 0, stream>>>(xqkv, tab, xq, xk);
  k_vt<<<dim3(16, 64), dim3(32, 8), 0, stream>>>(xqkv, xvT);

  k_attn<<<256, 256, 0, stream>>>(xq, xk, xvT, attnout);

  k_gemm<DIM, true><<<dim3(DIM / 128, SEQ / 128), 256, 0, stream>>>(attnout, woT, out);
}